// Round 10
// baseline (86.092 us; speedup 1.0000x reference)
//
#include <hip/hip_runtime.h>
#include <math.h>

// Luong attention, fused single pass over enc (read exactly once).
// R10: DS-pipe relief. R8 probe arithmetic: 1727 cy/wave-step vs ~190 issue
// cycles, no pipe >36% EXCEPT the shared per-CU LDS pipe: 6 ds_swizzle/row
// across 32 waves/CU saturates it at ~the measured 9.5 B/cy/CU. New layout:
// 32-lane groups (lane owns 8 cols, group owns one row/step); score reduce =
// 4 DPP row_ror adds (VALU pipe!) + 1 ds_swizzle xor16. DS/row: 6 -> 0.5.
// ~50 VGPR keeps 8 blocks/CU (R5's register-blowup lesson).

#define WPB 4
#define BLOCK 256
#define D 256

#define DPP_ADD(x, ctrl) ((x) + __int_as_float(__builtin_amdgcn_update_dpp( \
    0, __float_as_int(x), (ctrl), 0xF, 0xF, false)))

__device__ __forceinline__ float reduce32(float p) {
    p = DPP_ADD(p, 0x128);   // row_ror:8   (VALU)
    p = DPP_ADD(p, 0x124);   // row_ror:4   (VALU)
    p = DPP_ADD(p, 0x122);   // row_ror:2   (VALU)
    p = DPP_ADD(p, 0x121);   // row_ror:1 -> sum within each 16
    // xor16 within each 32-half: the only DS op (0.5 per row)
    p += __int_as_float(__builtin_amdgcn_ds_swizzle(__float_as_int(p), 0x401F));
    return p;
}

// Kernel 1: per-WAVE partial with online softmax (no intra-block combine, no
// __syncthreads). ws layout: pacc[nw_total][D] floats, then ml[nw_total][2].
__global__ __launch_bounds__(BLOCK) void attn_partial(
    const float* __restrict__ enc,   // [B,T,D]
    const float* __restrict__ dec,   // [B,D]
    float* __restrict__ ws,
    int T, int P, int nw_total)
{
    const int blk   = blockIdx.x;
    const int b     = blk / P;
    const int chunk = blk % P;
    const int tid   = threadIdx.x;
    const int wave  = tid >> 6;
    const int lane  = tid & 63;
    const int g     = lane >> 5;       // 32-lane group: owns one row per step
    const int c8    = (lane & 31) * 8; // lane's 8 columns

    const int rows_per_block = T / P;
    const int steps = rows_per_block / (WPB * 2);  // 2 rows per block-wave-step

    const float* __restrict__ encb = enc + (size_t)b * T * D;
    const float* __restrict__ decb = dec + (size_t)b * D;

    const float4 dq0 = *reinterpret_cast<const float4*>(decb + c8);
    const float4 dq1 = *reinterpret_cast<const float4*>(decb + c8 + 4);

    float  m = -INFINITY;
    float  l = 0.0f;
    float4 a0 = {0,0,0,0}, a1 = {0,0,0,0};

    // step s: group (wave,g) handles row chunk*rpb + s*8 + wave*2 + g
    // (block walks one contiguous 8-row/8KB stripe per step)
    const float* wbase = encb
        + (size_t)(chunk * rows_per_block + wave * 2 + g) * D + c8;

    #pragma unroll 2
    for (int s = 0; s < steps; ++s) {
        const float* rp = wbase + (size_t)s * (WPB * 2) * D;
        const float4 x0 = *reinterpret_cast<const float4*>(rp);
        const float4 x1 = *reinterpret_cast<const float4*>(rp + 4);

        float p = x0.x*dq0.x + x0.y*dq0.y + x0.z*dq0.z + x0.w*dq0.w;
        p = fmaf(x1.x, dq1.x, fmaf(x1.y, dq1.y, fmaf(x1.z, dq1.z, fmaf(x1.w, dq1.w, p))));
        p = reduce32(p);                  // group-row score, group-uniform

        const float mn    = fmaxf(m, p);
        const float scale = __expf(m - mn);   // 0 when m == -inf
        const float w     = __expf(p - mn);

        a0.x = fmaf(w, x0.x, a0.x * scale); a0.y = fmaf(w, x0.y, a0.y * scale);
        a0.z = fmaf(w, x0.z, a0.z * scale); a0.w = fmaf(w, x0.w, a0.w * scale);
        a1.x = fmaf(w, x1.x, a1.x * scale); a1.y = fmaf(w, x1.y, a1.y * scale);
        a1.z = fmaf(w, x1.z, a1.z * scale); a1.w = fmaf(w, x1.w, a1.w * scale);
        l = fmaf(l, scale, w);
        m = mn;
    }

    // ---- merge the two 32-lane groups (once per wave, ~10 shuffles) ----
    const float mo = __shfl_xor(m, 32, 64);
    const float M  = fmaxf(m, mo);
    const float e  = __expf(m - M);
    l *= e;
    a0.x *= e; a0.y *= e; a0.z *= e; a0.w *= e;
    a1.x *= e; a1.y *= e; a1.z *= e; a1.w *= e;

    l    += __shfl_xor(l,    32, 64);
    a0.x += __shfl_xor(a0.x, 32, 64);
    a0.y += __shfl_xor(a0.y, 32, 64);
    a0.z += __shfl_xor(a0.z, 32, 64);
    a0.w += __shfl_xor(a0.w, 32, 64);
    a1.x += __shfl_xor(a1.x, 32, 64);
    a1.y += __shfl_xor(a1.y, 32, 64);
    a1.z += __shfl_xor(a1.z, 32, 64);
    a1.w += __shfl_xor(a1.w, 32, 64);

    // lane<32 writes its a0 at col lane*8; lane>=32 writes its a1 at +4
    const int wid = blk * WPB + wave;
    const float4 v = (lane < 32) ? a0 : a1;
    *reinterpret_cast<float4*>(ws + (size_t)wid * D + c8 + (g << 2)) = v;
    if (lane == 0) {
        float* ml = ws + (size_t)nw_total * D;
        ml[wid * 2 + 0] = M;
        ml[wid * 2 + 1] = l;
    }
}

// Kernel 2: combine nw per-wave partials per batch, normalize, write out.
// grid = B*4 blocks; block handles one 64-column quarter.
__global__ __launch_bounds__(BLOCK) void attn_combine(
    const float* __restrict__ ws,
    float* __restrict__ out,
    int nw, int nw_total)
{
    const int b     = blockIdx.x >> 2;
    const int cq    = blockIdx.x & 3;
    const int tid   = threadIdx.x;
    const int lane  = tid & 63;
    const int slice = tid >> 6;
    const int col   = cq * 64 + lane;
    const int i0    = b * nw;

    const float* __restrict__ ml = ws + (size_t)nw_total * D;

    __shared__ float sM[4];
    __shared__ float sL[4];
    __shared__ float sA[4][64];

    float Mw = -INFINITY;
    for (int i = slice; i < nw; i += 4)
        Mw = fmaxf(Mw, ml[(i0 + i) * 2 + 0]);
    if (lane == 0) sM[slice] = Mw;
    __syncthreads();
    const float M = fmaxf(fmaxf(sM[0], sM[1]), fmaxf(sM[2], sM[3]));

    float a = 0.0f, L = 0.0f;
    for (int i = slice; i < nw; i += 4) {
        const int pid = i0 + i;
        const float e = __expf(ml[pid * 2 + 0] - M);
        a = fmaf(e, ws[(size_t)pid * D + col], a);
        L = fmaf(e, ml[pid * 2 + 1], L);
    }
    sA[slice][lane] = a;
    if (lane == 0) sL[slice] = L;
    __syncthreads();

    if (slice == 0) {
        const float at = sA[0][lane] + sA[1][lane] + sA[2][lane] + sA[3][lane];
        const float Lt = sL[0] + sL[1] + sL[2] + sL[3];
        out[b * D + col] = at / Lt;
    }
}

extern "C" void kernel_launch(void* const* d_in, const int* in_sizes, int n_in,
                              void* d_out, int out_size, void* d_ws, size_t ws_size,
                              hipStream_t stream) {
    const float* enc = (const float*)d_in[0];
    const float* dec = (const float*)d_in[1];
    float* out = (float*)d_out;
    float* ws  = (float*)d_ws;

    const int B = in_sizes[1] / D;              // dec is [B, D]
    const int T = in_sizes[0] / in_sizes[1];    // enc is [B, T, D]

    // P chunks per batch; shrink if workspace too small or shape not divisible.
    int P = 64;
    while (P > 1 && ((size_t)B * P * WPB * (D + 2) * sizeof(float)) > ws_size) P >>= 1;
    while (P > 1 && (T % (P * WPB * 2) != 0)) P >>= 1;

    const int nblk     = B * P;
    const int nw_total = nblk * WPB;
    attn_partial<<<nblk, BLOCK, 0, stream>>>(enc, dec, ws, T, P, nw_total);
    attn_combine<<<B * 4, BLOCK, 0, stream>>>(ws, out, P * WPB, nw_total);
}

// Round 12
// 60.947 us; speedup vs baseline: 1.4126x; 1.4126x over previous
//
#include <hip/hip_runtime.h>
#include <math.h>

// Luong attention, fused single pass over enc (read exactly once).
// R12 = R11 with the compile fix: __builtin_nontemporal_load needs a clang
// native vector type (ext_vector_type), not HIP's struct float4.
// Testing: does bypassing L3 allocation (nt loads) lift the ~5.75 TB/s
// logical-read cap (theory B), or is the XCD fabric port the hard limit
// (theory A -> null)?
// NOTE (R5/R10 lesson): keep load shape = 64 lanes x 16B = one 1KB row per
// instruction; layout changes that fragment this cost ~45%.

#define WAVES_PER_BLOCK 4
#define BLOCK 256
#define D 256
#define RBATCH 4

typedef float fx4 __attribute__((ext_vector_type(4)));

__device__ __forceinline__ float4 ntload(const float* p) {
    fx4 v = __builtin_nontemporal_load(reinterpret_cast<const fx4*>(p));
    float4 r; r.x = v.x; r.y = v.y; r.z = v.z; r.w = v.w;
    return r;
}

// Kernel 1: per-(batch,chunk) partial with online softmax.
// ws layout: acc[B*P][256] floats, then interleaved (m,l)[B*P][2].
__global__ __launch_bounds__(BLOCK) void attn_partial(
    const float* __restrict__ enc,   // [B,T,D]
    const float* __restrict__ dec,   // [B,D]
    float* __restrict__ ws,
    int T, int P, int nblk_total)
{
    const int blk   = blockIdx.x;
    const int b     = blk / P;
    const int chunk = blk % P;
    const int tid   = threadIdx.x;
    const int wave  = tid >> 6;
    const int lane  = tid & 63;

    const int rows_per_block = T / P;
    const int steps = rows_per_block / (WAVES_PER_BLOCK * RBATCH);

    const float* __restrict__ encb = enc + (size_t)b * T * D;
    const float4 dq = *reinterpret_cast<const float4*>(dec + b * D + lane * 4);

    float  m = -INFINITY;
    float  l = 0.0f;
    float4 acc = {0.0f, 0.0f, 0.0f, 0.0f};

    // step s: wave handles rows chunk*rpb + s*16 + wave*4 .. +3 (block walks
    // one contiguous 16KB stripe per step -- R7's stream consolidation)
    const float* wbase = encb
        + (size_t)(chunk * rows_per_block + wave * RBATCH) * D + lane * 4;

    #pragma unroll 2
    for (int s = 0; s < steps; ++s) {
        const float* base = wbase + (size_t)s * (WAVES_PER_BLOCK * RBATCH) * D;
        const float4 x0 = ntload(base);
        const float4 x1 = ntload(base + D);
        const float4 x2 = ntload(base + 2 * D);
        const float4 x3 = ntload(base + 3 * D);

        float p0 = dq.x * x0.x + dq.y * x0.y + dq.z * x0.z + dq.w * x0.w;
        float p1 = dq.x * x1.x + dq.y * x1.y + dq.z * x1.z + dq.w * x1.w;
        float p2 = dq.x * x2.x + dq.y * x2.y + dq.z * x2.z + dq.w * x2.w;
        float p3 = dq.x * x3.x + dq.y * x3.y + dq.z * x3.z + dq.w * x3.w;

        #pragma unroll
        for (int off = 32; off >= 1; off >>= 1) {
            p0 += __shfl_xor(p0, off, 64);
            p1 += __shfl_xor(p1, off, 64);
            p2 += __shfl_xor(p2, off, 64);
            p3 += __shfl_xor(p3, off, 64);
        }

        const float mn    = fmaxf(fmaxf(fmaxf(p0, p1), fmaxf(p2, p3)), m);
        const float scale = __expf(m - mn);   // 0 when m == -inf
        const float w0 = __expf(p0 - mn);
        const float w1 = __expf(p1 - mn);
        const float w2 = __expf(p2 - mn);
        const float w3 = __expf(p3 - mn);

        acc.x = fmaf(w3, x3.x, fmaf(w2, x2.x, fmaf(w1, x1.x, fmaf(w0, x0.x, acc.x * scale))));
        acc.y = fmaf(w3, x3.y, fmaf(w2, x2.y, fmaf(w1, x1.y, fmaf(w0, x0.y, acc.y * scale))));
        acc.z = fmaf(w3, x3.z, fmaf(w2, x2.z, fmaf(w1, x1.z, fmaf(w0, x0.z, acc.z * scale))));
        acc.w = fmaf(w3, x3.w, fmaf(w2, x2.w, fmaf(w1, x1.w, fmaf(w0, x0.w, acc.w * scale))));
        l = fmaf(l, scale, w0 + w1 + w2 + w3);
        m = mn;
    }

    // combine the 4 waves' partials in LDS -> one partial per block
    __shared__ float s_acc[WAVES_PER_BLOCK][D];
    __shared__ float s_m[WAVES_PER_BLOCK];
    __shared__ float s_l[WAVES_PER_BLOCK];

    *reinterpret_cast<float4*>(&s_acc[wave][lane * 4]) = acc;
    if (lane == 0) { s_m[wave] = m; s_l[wave] = l; }
    __syncthreads();

    if (wave == 0) {
        const float M = fmaxf(fmaxf(s_m[0], s_m[1]), fmaxf(s_m[2], s_m[3]));
        float4 a = {0.0f, 0.0f, 0.0f, 0.0f};
        float  L = 0.0f;
        #pragma unroll
        for (int wv = 0; wv < WAVES_PER_BLOCK; ++wv) {
            const float e = __expf(s_m[wv] - M);
            const float4 aw = *reinterpret_cast<const float4*>(&s_acc[wv][lane * 4]);
            a.x += e * aw.x; a.y += e * aw.y; a.z += e * aw.z; a.w += e * aw.w;
            L += e * s_l[wv];
        }
        *reinterpret_cast<float4*>(ws + (size_t)blk * D + lane * 4) = a;
        if (lane == 0) {
            float* ml = ws + (size_t)nblk_total * D;
            ml[blk * 2 + 0] = M;
            ml[blk * 2 + 1] = L;
        }
    }
}

// Kernel 2: combine P partials per batch, normalize, write out.
// grid = B*4 blocks; block handles one 64-column quarter;
// 4 wave-slices stride the P loop, LDS reduce.
__global__ __launch_bounds__(BLOCK) void attn_combine(
    const float* __restrict__ ws,
    float* __restrict__ out,
    int P, int nblk_total)
{
    const int b     = blockIdx.x >> 2;
    const int cq    = blockIdx.x & 3;
    const int tid   = threadIdx.x;
    const int lane  = tid & 63;
    const int slice = tid >> 6;
    const int col   = cq * 64 + lane;

    const float* __restrict__ ml = ws + (size_t)nblk_total * D;

    float M = -INFINITY;
    for (int i = 0; i < P; ++i)
        M = fmaxf(M, ml[(b * P + i) * 2 + 0]);

    float a = 0.0f, L = 0.0f;
    for (int i = slice; i < P; i += 4) {
        const int pblk = b * P + i;
        const float e  = __expf(ml[pblk * 2 + 0] - M);
        a = fmaf(e, ws[(size_t)pblk * D + col], a);
        L = fmaf(e, ml[pblk * 2 + 1], L);
    }

    __shared__ float s_a[4][64];
    __shared__ float s_L[4];
    s_a[slice][lane] = a;
    if (lane == 0) s_L[slice] = L;
    __syncthreads();

    if (slice == 0) {
        const float at = s_a[0][lane] + s_a[1][lane] + s_a[2][lane] + s_a[3][lane];
        const float Lt = s_L[0] + s_L[1] + s_L[2] + s_L[3];
        out[b * D + col] = at / Lt;
    }
}

extern "C" void kernel_launch(void* const* d_in, const int* in_sizes, int n_in,
                              void* d_out, int out_size, void* d_ws, size_t ws_size,
                              hipStream_t stream) {
    const float* enc = (const float*)d_in[0];
    const float* dec = (const float*)d_in[1];
    float* out = (float*)d_out;
    float* ws  = (float*)d_ws;

    const int B = in_sizes[1] / D;              // dec is [B, D]
    const int T = in_sizes[0] / in_sizes[1];    // enc is [B, T, D]

    // P chunks per batch; shrink if workspace is small or shape not divisible.
    int P = 64;
    while (P > 1 && ((size_t)B * P * (D + 2) * sizeof(float)) > ws_size) P >>= 1;
    while (P > 1 && (T % (P * WAVES_PER_BLOCK * RBATCH) != 0)) P >>= 1;

    const int nblk = B * P;
    attn_partial<<<nblk, BLOCK, 0, stream>>>(enc, dec, ws, T, P, nblk);
    attn_combine<<<B * 4, BLOCK, 0, stream>>>(ws, out, P, nblk);
}

// Round 13
// 58.571 us; speedup vs baseline: 1.4699x; 1.0406x over previous
//
#include <hip/hip_runtime.h>
#include <math.h>

// Luong attention, fused single pass over enc (read exactly once).
// FINAL = R7 (measured best, 58.4us). scores=dec.enc row-dot, online softmax,
// weighted accumulation; per-block partials; parallel combine kernel.
//
// Why this is the roofline (session evidence):
//  - logical bytes minimal: 268MB enc read once (FETCH_SIZE confirms).
//  - R8 4x-probe: k1 sustains 5.75 TB/s logical (L3 serves ~half), with
//    HBM 36%, VALU 20%, DS ~30% -- no pipe saturated; latency-tolerant.
//  - nulls: register prefetch (R9), nt loads (R12, -2.5us: loses L3 replay
//    hits), DS-pipe relief via DPP (R10, confounded by coalescing break).
//  - regressions understood: per-block __threadfence (R3, 5x), 64-VGPR
//    occupancy cliff / 4x register layouts (R5/R6), fragmented 16B-hole
//    loads (R5/R10, ~45%).
//  - structure: k1 ~52us (= 268MB @ ~5.2 TB/s incl. ramp), k2 ~1.5us,
//    graph+launch ~4-5us.

#define WAVES_PER_BLOCK 4
#define BLOCK 256
#define D 256
#define RBATCH 4

// Kernel 1: per-(batch,chunk) partial with online softmax.
// ws layout: acc[B*P][256] floats, then interleaved (m,l)[B*P][2].
__global__ __launch_bounds__(BLOCK) void attn_partial(
    const float* __restrict__ enc,   // [B,T,D]
    const float* __restrict__ dec,   // [B,D]
    float* __restrict__ ws,
    int T, int P, int nblk_total)
{
    const int blk   = blockIdx.x;
    const int b     = blk / P;
    const int chunk = blk % P;
    const int tid   = threadIdx.x;
    const int wave  = tid >> 6;
    const int lane  = tid & 63;

    const int rows_per_block = T / P;
    const int steps = rows_per_block / (WAVES_PER_BLOCK * RBATCH);

    const float* __restrict__ encb = enc + (size_t)b * T * D;
    const float4 dq = *reinterpret_cast<const float4*>(dec + b * D + lane * 4);

    float  m = -INFINITY;
    float  l = 0.0f;
    float4 acc = {0.0f, 0.0f, 0.0f, 0.0f};

    // step s: wave handles rows chunk*rpb + s*16 + wave*4 .. +3 (block walks
    // one contiguous 16KB stripe per step; 64 lanes x 16B = one 1KB row per
    // load instruction -- do not fragment this shape)
    const float* wbase = encb
        + (size_t)(chunk * rows_per_block + wave * RBATCH) * D + lane * 4;

    #pragma unroll 2
    for (int s = 0; s < steps; ++s) {
        const float* base = wbase + (size_t)s * (WAVES_PER_BLOCK * RBATCH) * D;
        const float4 x0 = *reinterpret_cast<const float4*>(base);
        const float4 x1 = *reinterpret_cast<const float4*>(base + D);
        const float4 x2 = *reinterpret_cast<const float4*>(base + 2 * D);
        const float4 x3 = *reinterpret_cast<const float4*>(base + 3 * D);

        float p0 = dq.x * x0.x + dq.y * x0.y + dq.z * x0.z + dq.w * x0.w;
        float p1 = dq.x * x1.x + dq.y * x1.y + dq.z * x1.z + dq.w * x1.w;
        float p2 = dq.x * x2.x + dq.y * x2.y + dq.z * x2.z + dq.w * x2.w;
        float p3 = dq.x * x3.x + dq.y * x3.y + dq.z * x3.z + dq.w * x3.w;

        #pragma unroll
        for (int off = 32; off >= 1; off >>= 1) {
            p0 += __shfl_xor(p0, off, 64);
            p1 += __shfl_xor(p1, off, 64);
            p2 += __shfl_xor(p2, off, 64);
            p3 += __shfl_xor(p3, off, 64);
        }

        const float mn    = fmaxf(fmaxf(fmaxf(p0, p1), fmaxf(p2, p3)), m);
        const float scale = __expf(m - mn);   // 0 when m == -inf
        const float w0 = __expf(p0 - mn);
        const float w1 = __expf(p1 - mn);
        const float w2 = __expf(p2 - mn);
        const float w3 = __expf(p3 - mn);

        acc.x = fmaf(w3, x3.x, fmaf(w2, x2.x, fmaf(w1, x1.x, fmaf(w0, x0.x, acc.x * scale))));
        acc.y = fmaf(w3, x3.y, fmaf(w2, x2.y, fmaf(w1, x1.y, fmaf(w0, x0.y, acc.y * scale))));
        acc.z = fmaf(w3, x3.z, fmaf(w2, x2.z, fmaf(w1, x1.z, fmaf(w0, x0.z, acc.z * scale))));
        acc.w = fmaf(w3, x3.w, fmaf(w2, x2.w, fmaf(w1, x1.w, fmaf(w0, x0.w, acc.w * scale))));
        l = fmaf(l, scale, w0 + w1 + w2 + w3);
        m = mn;
    }

    // combine the 4 waves' partials in LDS -> one partial per block
    __shared__ float s_acc[WAVES_PER_BLOCK][D];
    __shared__ float s_m[WAVES_PER_BLOCK];
    __shared__ float s_l[WAVES_PER_BLOCK];

    *reinterpret_cast<float4*>(&s_acc[wave][lane * 4]) = acc;
    if (lane == 0) { s_m[wave] = m; s_l[wave] = l; }
    __syncthreads();

    if (wave == 0) {
        const float M = fmaxf(fmaxf(s_m[0], s_m[1]), fmaxf(s_m[2], s_m[3]));
        float4 a = {0.0f, 0.0f, 0.0f, 0.0f};
        float  L = 0.0f;
        #pragma unroll
        for (int wv = 0; wv < WAVES_PER_BLOCK; ++wv) {
            const float e = __expf(s_m[wv] - M);
            const float4 aw = *reinterpret_cast<const float4*>(&s_acc[wv][lane * 4]);
            a.x += e * aw.x; a.y += e * aw.y; a.z += e * aw.z; a.w += e * aw.w;
            L += e * s_l[wv];
        }
        *reinterpret_cast<float4*>(ws + (size_t)blk * D + lane * 4) = a;
        if (lane == 0) {
            float* ml = ws + (size_t)nblk_total * D;
            ml[blk * 2 + 0] = M;
            ml[blk * 2 + 1] = L;
        }
    }
}

// Kernel 2: combine P partials per batch, normalize, write out.
// grid = B*4 blocks; block handles one 64-column quarter;
// 4 wave-slices stride the P loop, LDS reduce.
__global__ __launch_bounds__(BLOCK) void attn_combine(
    const float* __restrict__ ws,
    float* __restrict__ out,
    int P, int nblk_total)
{
    const int b     = blockIdx.x >> 2;
    const int cq    = blockIdx.x & 3;
    const int tid   = threadIdx.x;
    const int lane  = tid & 63;
    const int slice = tid >> 6;
    const int col   = cq * 64 + lane;

    const float* __restrict__ ml = ws + (size_t)nblk_total * D;

    float M = -INFINITY;
    for (int i = 0; i < P; ++i)
        M = fmaxf(M, ml[(b * P + i) * 2 + 0]);

    float a = 0.0f, L = 0.0f;
    for (int i = slice; i < P; i += 4) {
        const int pblk = b * P + i;
        const float e  = __expf(ml[pblk * 2 + 0] - M);
        a = fmaf(e, ws[(size_t)pblk * D + col], a);
        L = fmaf(e, ml[pblk * 2 + 1], L);
    }

    __shared__ float s_a[4][64];
    __shared__ float s_L[4];
    s_a[slice][lane] = a;
    if (lane == 0) s_L[slice] = L;
    __syncthreads();

    if (slice == 0) {
        const float at = s_a[0][lane] + s_a[1][lane] + s_a[2][lane] + s_a[3][lane];
        const float Lt = s_L[0] + s_L[1] + s_L[2] + s_L[3];
        out[b * D + col] = at / Lt;
    }
}

extern "C" void kernel_launch(void* const* d_in, const int* in_sizes, int n_in,
                              void* d_out, int out_size, void* d_ws, size_t ws_size,
                              hipStream_t stream) {
    const float* enc = (const float*)d_in[0];
    const float* dec = (const float*)d_in[1];
    float* out = (float*)d_out;
    float* ws  = (float*)d_ws;

    const int B = in_sizes[1] / D;              // dec is [B, D]
    const int T = in_sizes[0] / in_sizes[1];    // enc is [B, T, D]

    // P chunks per batch; shrink if workspace is small or shape not divisible.
    int P = 64;
    while (P > 1 && ((size_t)B * P * (D + 2) * sizeof(float)) > ws_size) P >>= 1;
    while (P > 1 && (T % (P * WAVES_PER_BLOCK * RBATCH) != 0)) P >>= 1;

    const int nblk = B * P;
    attn_partial<<<nblk, BLOCK, 0, stream>>>(enc, dec, ws, T, P, nblk);
    attn_combine<<<B * 4, BLOCK, 0, stream>>>(ws, out, P, nblk);
}